// Round 1
// baseline (213.442 us; speedup 1.0000x reference)
//
#include <hip/hip_runtime.h>

// SteeredConv2d: out[n,o,h,w] = bias[o] + sum_i ( W[o,i,0]*f0 + W[o,i,1]*f1
//                                              + W[o,i,2]*f2 + W[o,i,3]*f3 )
// where f0..f3 are 3x3 stencil features of x[n,i,:,:] with per-pixel angle
// coefficients c1,s1,c2,s2 from theta. Exact radial basis taps:
//   b1 (ring)      : sqrt(1/8) on all 8 ring taps
//   b2 (cos a)     : +-sqrt(2)/4 on diagonals, +-0.5 on x-axis
//   b3 (sin a)     : +-sqrt(2)/4 on diagonals, +-0.5 on y-axis
//   b4 (cos 2a)    : +0.5 x-axis, -0.5 y-axis
//   b5 (sin 2a)    : +0.5 main diag, -0.5 anti-diag

#define TH 4
#define TW 64
#define CH_CHUNK 16
#define C_IN 64
#define C_OUT 64
#define HH 128
#define WW 128

__global__ __launch_bounds__(256, 4) void steered_conv_kernel(
    const float* __restrict__ x, const float* __restrict__ theta,
    const float* __restrict__ wt, const float* __restrict__ bias,
    float* __restrict__ out)
{
    constexpr int ROW  = TW + 2;        // 66
    constexpr int CHSZ = (TH + 2) * ROW; // 396
    __shared__ float lds[CH_CHUNK * CHSZ];

    const int tid = threadIdx.x;
    const int tx  = tid & 63;
    const int ty  = tid >> 6;
    const int w0  = blockIdx.x * TW;
    const int h0  = blockIdx.y * TH;
    const int n   = blockIdx.z;
    const int h   = h0 + ty, w = w0 + tx;

    // per-pixel angle harmonics
    const float a = 6.2831853071795864769f * theta[(n * HH + h) * WW + w];
    float s1, c1;
    __sincosf(a, &s1, &c1);
    const float c2 = 2.f * c1 * c1 - 1.f;
    const float s2 = 2.f * s1 * c1;

    float acc[C_OUT];
    #pragma unroll
    for (int o = 0; o < C_OUT; ++o) acc[o] = bias[o];

    for (int cc = 0; cc < C_IN / CH_CHUNK; ++cc) {
        const int c0 = cc * CH_CHUNK;
        __syncthreads();  // previous chunk's readers done before overwrite
        for (int idx = tid; idx < CH_CHUNK * CHSZ; idx += 256) {
            const int c   = idx / CHSZ;
            const int rem = idx - c * CHSZ;
            const int yy  = rem / ROW;
            const int xx  = rem - yy * ROW;
            const int gh  = h0 + yy - 1;
            const int gw  = w0 + xx - 1;
            float v = 0.f;
            if ((unsigned)gh < (unsigned)HH && (unsigned)gw < (unsigned)WW)
                v = x[(((n * C_IN) + c0 + c) * HH + gh) * WW + gw];
            lds[idx] = v;
        }
        __syncthreads();

        #pragma unroll 1
        for (int i = 0; i < CH_CHUNK; ++i) {
            const float* p = &lds[i * CHSZ + ty * ROW + tx];
            const float t00 = p[0],       t01 = p[1],           t02 = p[2];
            const float t10 = p[ROW],     t11 = p[ROW + 1],     t12 = p[ROW + 2];
            const float t20 = p[2 * ROW], t21 = p[2 * ROW + 1], t22 = p[2 * ROW + 2];

            const float RS = 0.35355339059327373f;  // sqrt(1/8) == sqrt(2)/4
            const float f0 = t11;
            const float f1 = RS * (t00 + t01 + t02 + t10 + t12 + t20 + t21 + t22);
            const float f2 = c1 * (RS * ((t02 - t00) + (t22 - t20)) + 0.5f * (t12 - t10))
                           + s1 * (RS * ((t20 + t22) - (t00 + t02)) + 0.5f * (t21 - t01));
            const float f3 = c2 * (0.5f * ((t10 + t12) - (t01 + t21)))
                           + s2 * (0.5f * ((t00 + t22) - (t02 + t20)));

            const int ic = c0 + i;
            const float* wp = wt + ic * 4;  // uniform -> scalar loads
            #pragma unroll
            for (int o = 0; o < C_OUT; ++o) {
                const float* wo = wp + o * (C_IN * 4);
                acc[o] += wo[0] * f0 + wo[1] * f1 + wo[2] * f2 + wo[3] * f3;
            }
        }
    }

    float* op = out + ((size_t)(n * C_OUT) * HH + h) * WW + w;
    #pragma unroll
    for (int o = 0; o < C_OUT; ++o)
        op[(size_t)o * HH * WW] = acc[o];
}

extern "C" void kernel_launch(void* const* d_in, const int* in_sizes, int n_in,
                              void* d_out, int out_size, void* d_ws, size_t ws_size,
                              hipStream_t stream) {
    const float* x     = (const float*)d_in[0];
    const float* theta = (const float*)d_in[1];
    const float* wt    = (const float*)d_in[2];
    const float* bias  = (const float*)d_in[3];
    float* out = (float*)d_out;
    const int N = 16;
    dim3 grid(WW / TW, HH / TH, N);
    steered_conv_kernel<<<grid, 256, 0, stream>>>(x, theta, wt, bias, out);
}

// Round 2
// 95.473 us; speedup vs baseline: 2.2356x; 2.2356x over previous
//
#include <hip/hip_runtime.h>

// Steered conv as per-pixel GEMM: out[o,pix] = bias[o] + sum_k W[o,k] * F[k,pix]
//   k = i*4 + p, K = 256; F features from 3x3 stencil + per-pixel harmonics.
// MFMA v_mfma_f32_32x32x16_bf16: A = weights (o x k), B = features (k x pix).
// B-frag layout: lane l -> col = l&31 (pixel), k = 16*kc + 8*(l>>5) + r.
// A-frag layout: lane l -> row = l&31 (o within 32-tile), same k.
// C/D layout: col = lane&31 (pixel), row(o) = (r&3) + 8*(r>>2) + 4*(lane>>5).

typedef __bf16 bf16x8 __attribute__((ext_vector_type(8)));
typedef float f32x16 __attribute__((ext_vector_type(16)));

#define C_IN 64
#define C_OUT 64
#define HH 128
#define WW 128
#define TILE_H 4
#define TILE_W 32
#define ROWS (TILE_H + 2)        // 6
#define COLS (TILE_W + 2)        // 34
#define CH_ELEMS (ROWS * COLS)   // 204
#define CH_STRIDE 208            // 208 % 32 == 16 -> the 2 lane-halves (ch, ch+2)
                                 // hit disjoint bank halves: <=2-way (free)

__device__ __forceinline__ float bf2f(unsigned short u) {
    union { unsigned u; float f; } v; v.u = ((unsigned)u) << 16; return v.f;
}

// One-time (per launch) weight f32 -> bf16 repack into d_ws. 16384 elems.
__global__ void wt_to_bf16(const float* __restrict__ wt,
                           unsigned short* __restrict__ wb) {
    int i = blockIdx.x * 256 + threadIdx.x;
    union { float f; unsigned u; } v; v.f = wt[i];
    wb[i] = (unsigned short)((v.u + 0x7FFF + ((v.u >> 16) & 1)) >> 16);
}

__global__ __launch_bounds__(256, 4) void steered_conv_mfma(
    const float* __restrict__ x, const float* __restrict__ theta,
    const unsigned short* __restrict__ wb, const float* __restrict__ bias,
    float* __restrict__ out)
{
    __shared__ unsigned short xt[C_IN * CH_STRIDE];   // 26.6 KB

    const int tid = threadIdx.x;
    const int n  = blockIdx.z;
    const int h0 = blockIdx.y * TILE_H;
    const int w0 = blockIdx.x * TILE_W;

    // ---- stage x tile (all 64 ch, 6x34 halo'd rows) as bf16; one barrier ----
    for (int idx = tid; idx < C_IN * CH_ELEMS; idx += 256) {
        int ch  = idx / CH_ELEMS;
        int rem = idx - ch * CH_ELEMS;
        int row = rem / COLS;
        int col = rem - row * COLS;
        int gh = h0 + row - 1;
        int gw = w0 + col - 1;
        float v = 0.f;
        if ((unsigned)gh < (unsigned)HH && (unsigned)gw < (unsigned)WW)
            v = x[(((n * C_IN) + ch) * HH + gh) * WW + gw];
        union { float f; unsigned u; } uv; uv.f = v;
        xt[ch * CH_STRIDE + row * COLS + col] =
            (unsigned short)((uv.u + 0x7FFF + ((uv.u >> 16) & 1)) >> 16);
    }
    __syncthreads();

    const int wid  = tid >> 6;     // wave id -> output row within tile
    const int lane = tid & 63;
    const int pc   = lane & 31;    // pixel col (MFMA col index)
    const int hx   = lane >> 5;    // k-half

    const int h = h0 + wid;
    const int w = w0 + pc;

    const float ang = 6.2831853071795864769f * theta[(n * HH + h) * WW + w];
    float s1, c1;
    __sincosf(ang, &s1, &c1);
    const float c2 = 2.f * c1 * c1 - 1.f;
    const float s2 = 2.f * s1 * c1;

    f32x16 acc0, acc1;
    #pragma unroll
    for (int r = 0; r < 16; ++r) { acc0[r] = 0.f; acc1[r] = 0.f; }

    const unsigned short* xw = &xt[wid * COLS + pc];
    const float RS = 0.35355339059327373f;   // sqrt(2)/4

    #pragma unroll 2
    for (int kc = 0; kc < 16; ++kc) {
        bf16x8 b;
        #pragma unroll
        for (int cs = 0; cs < 2; ++cs) {
            const unsigned short* p = xw + (kc * 4 + hx * 2 + cs) * CH_STRIDE;
            float t00 = bf2f(p[0]);
            float t01 = bf2f(p[1]);
            float t02 = bf2f(p[2]);
            float t10 = bf2f(p[COLS]);
            float t11 = bf2f(p[COLS + 1]);
            float t12 = bf2f(p[COLS + 2]);
            float t20 = bf2f(p[2 * COLS]);
            float t21 = bf2f(p[2 * COLS + 1]);
            float t22 = bf2f(p[2 * COLS + 2]);
            float f1 = RS * (t00 + t01 + t02 + t10 + t12 + t20 + t21 + t22);
            float f2 = c1 * (RS * ((t02 - t00) + (t22 - t20)) + 0.5f * (t12 - t10))
                     + s1 * (RS * ((t20 + t22) - (t00 + t02)) + 0.5f * (t21 - t01));
            float f3 = c2 * (0.5f * ((t10 + t12) - (t01 + t21)))
                     + s2 * (0.5f * ((t00 + t22) - (t02 + t20)));
            b[cs * 4 + 0] = (__bf16)t11;  // f0 = center tap
            b[cs * 4 + 1] = (__bf16)f1;
            b[cs * 4 + 2] = (__bf16)f2;
            b[cs * 4 + 3] = (__bf16)f3;
        }
        // A fragments: wt_bf16[o][k], o = 32m + pc, k = kc*16 + hx*8 + r
        const unsigned short* wr = wb + pc * 256 + kc * 16 + hx * 8;
        bf16x8 a0 = *(const bf16x8*)(wr);
        bf16x8 a1 = *(const bf16x8*)(wr + 32 * 256);
        acc0 = __builtin_amdgcn_mfma_f32_32x32x16_bf16(a0, b, acc0, 0, 0, 0);
        acc1 = __builtin_amdgcn_mfma_f32_32x32x16_bf16(a1, b, acc1, 0, 0, 0);
    }

    const size_t hw = (size_t)HH * WW;
    float* op = out + (size_t)n * C_OUT * hw + (size_t)h * WW + w;
    #pragma unroll
    for (int r = 0; r < 16; ++r) {
        int o0 = (r & 3) + 8 * (r >> 2) + 4 * hx;
        op[(size_t)o0 * hw] = acc0[r] + bias[o0];
        op[(size_t)(o0 + 32) * hw] = acc1[r] + bias[o0 + 32];
    }
}

extern "C" void kernel_launch(void* const* d_in, const int* in_sizes, int n_in,
                              void* d_out, int out_size, void* d_ws, size_t ws_size,
                              hipStream_t stream) {
    const float* x     = (const float*)d_in[0];
    const float* theta = (const float*)d_in[1];
    const float* wt    = (const float*)d_in[2];
    const float* bias  = (const float*)d_in[3];
    float* out = (float*)d_out;
    unsigned short* wb = (unsigned short*)d_ws;   // 32 KB bf16 weights

    wt_to_bf16<<<C_OUT * C_IN * 4 / 256, 256, 0, stream>>>(wt, wb);

    dim3 grid(WW / TILE_W, HH / TILE_H, 16);
    steered_conv_mfma<<<grid, 256, 0, stream>>>(x, theta, wb, bias, out);
}

// Round 3
// 79.704 us; speedup vs baseline: 2.6779x; 1.1978x over previous
//
#include <hip/hip_runtime.h>

// Steered conv as per-pixel GEMM: out[o,pix] = bias[o] + sum_k W[o,k] * F[k,pix]
//   k = ch*4 + feat, K = 256. F features from 3x3 stencil + per-pixel harmonics.
// MFMA v_mfma_f32_32x32x16_bf16: A = weights (o x k), B = features (k x pix).
// B-frag: lane l -> col = l&31 (pixel), k = 16*kc + 8*(l>>5) + r  (verified r2).
// A-frag: lane l -> row(o) = l&31, same k.                        (verified r2)
// C/D:    col = lane&31 (pixel), row(o) = (r&3) + 8*(r>>2) + 4*(lane>>5).

typedef __bf16 bf16x8 __attribute__((ext_vector_type(8)));
typedef float  f32x16 __attribute__((ext_vector_type(16)));
typedef float  f32x4  __attribute__((ext_vector_type(4)));

#define C_IN 64
#define C_OUT 64
#define HH 128
#define WW 128
#define TILE_H 4
#define TILE_W 32
#define CHUNK 32                 // channels resident in LDS at a time
#define ROWS 6                   // TILE_H + 2 halo rows
#define COLSTRIDE 40             // f32 per LDS row (16B-aligned stores, pad)
#define CH_LDS (ROWS * COLSTRIDE) // 240 f32 per channel

// One-time weight f32 -> bf16 (RNE) repack into d_ws. 16384 elems.
__global__ void wt_to_bf16(const float* __restrict__ wt,
                           unsigned short* __restrict__ wb) {
    int i = blockIdx.x * 256 + threadIdx.x;
    union { float f; unsigned u; } v; v.f = wt[i];
    wb[i] = (unsigned short)((v.u + 0x7FFF + ((v.u >> 16) & 1)) >> 16);
}

__global__ __launch_bounds__(256, 4) void steered_conv_mfma(
    const float* __restrict__ x, const float* __restrict__ theta,
    const unsigned short* __restrict__ wb, const float* __restrict__ bias,
    float* __restrict__ out)
{
    __shared__ float xt[CHUNK * CH_LDS];       // 30.7 KB, f32, x-tile chunk

    const int tid = threadIdx.x;
    const int n  = blockIdx.z;
    const int h0 = blockIdx.y * TILE_H;
    const int w0 = blockIdx.x * TILE_W;

    const int wid  = tid >> 6;      // wave -> output row in tile
    const int lane = tid & 63;
    const int pc   = lane & 31;     // pixel column (MFMA col)
    const int hx   = lane >> 5;     // k-half
    const int h = h0 + wid, w = w0 + pc;

    // per-pixel harmonics
    const float ang = 6.2831853071795864769f * theta[(n * HH + h) * WW + w];
    float s1, c1;
    __sincosf(ang, &s1, &c1);
    const float c2 = 2.f * c1 * c1 - 1.f;
    const float s2 = 2.f * s1 * c1;

    // staging map: group sg stages channel (chunkbase + sg); 8 lanes/row
    const int sg = tid >> 3;        // 0..31
    const int ss = tid & 7;         // 0..7

    f32x16 acc0, acc1;
    #pragma unroll
    for (int r = 0; r < 16; ++r) { acc0[r] = 0.f; acc1[r] = 0.f; }

    const unsigned short* wbase = wb + pc * 256 + hx * 8;
    const float* pb0 = &xt[(hx * 2) * CH_LDS + wid * COLSTRIDE + pc + 3];
    const float RS = 0.35355339059327373f;   // sqrt(2)/4
    const float HMR = 0.5f - 0.35355339059327373f;

    #pragma unroll
    for (int cc = 0; cc < 2; ++cc) {
        __syncthreads();           // readers of previous chunk done
        // ---- stage chunk: 32 ch x 6 rows x 34 cols, f32, vectorized ----
        {
            const int ch_g = cc * CHUNK + sg;
            const float* xrow = x + ((size_t)(n * C_IN + ch_g) * HH) * WW;
            #pragma unroll
            for (int it = 0; it < ROWS; ++it) {
                const int gh = h0 + it - 1;
                const bool vr = (unsigned)gh < (unsigned)HH;
                f32x4 v = {0.f, 0.f, 0.f, 0.f};
                float eL = 0.f, eR = 0.f;
                if (vr) {
                    const float* r = xrow + gh * WW + w0;
                    v = *(const f32x4*)(r + 4 * ss);
                    if (ss == 0 && w0 > 0)        eL = r[-1];
                    if (ss == 7 && w0 + 32 < WW)  eR = r[32];
                }
                float* dst = &xt[sg * CH_LDS + it * COLSTRIDE];
                *(f32x4*)(dst + 4 + 4 * ss) = v;     // cols gw = w0+4ss.. (c=4+4ss)
                if (ss == 0) dst[3]  = eL;            // gw = w0-1
                if (ss == 7) dst[36] = eR;            // gw = w0+32
            }
        }
        __syncthreads();

        // ---- 8 K-chunks of 16 (4 channels each) ----
        #pragma unroll
        for (int kc = 0; kc < 8; ++kc) {
            bf16x8 b;
            #pragma unroll
            for (int cs = 0; cs < 2; ++cs) {
                const float* p = pb0 + (kc * 4 + cs) * CH_LDS;
                const float t00 = p[0];
                const float t01 = p[1];
                const float t02 = p[2];
                const float t10 = p[COLSTRIDE];
                const float t11 = p[COLSTRIDE + 1];
                const float t12 = p[COLSTRIDE + 2];
                const float t20 = p[2 * COLSTRIDE];
                const float t21 = p[2 * COLSTRIDE + 1];
                const float t22 = p[2 * COLSTRIDE + 2];

                const float Stp = t00 + t01 + t02;
                const float Sbt = t20 + t21 + t22;
                const float hdT = t02 - t00;
                const float hdB = t22 - t20;

                const float f1 = RS * (Stp + Sbt + t10 + t12);
                const float b2 = RS * (hdT + hdB) + 0.5f * (t12 - t10);
                const float b3 = RS * (Sbt - Stp) + HMR * (t21 - t01);
                const float b4 = 0.5f * ((t10 + t12) - (t01 + t21));
                const float b5 = 0.5f * (hdB - hdT);

                b[cs * 4 + 0] = (__bf16)t11;                  // f0
                b[cs * 4 + 1] = (__bf16)f1;                   // f1
                b[cs * 4 + 2] = (__bf16)(c1 * b2 + s1 * b3);  // f2
                b[cs * 4 + 3] = (__bf16)(c2 * b4 + s2 * b5);  // f3
            }
            const int kcg = cc * 8 + kc;
            bf16x8 a0 = *(const bf16x8*)(wbase + kcg * 16);
            bf16x8 a1 = *(const bf16x8*)(wbase + 32 * 256 + kcg * 16);
            acc0 = __builtin_amdgcn_mfma_f32_32x32x16_bf16(a0, b, acc0, 0, 0, 0);
            acc1 = __builtin_amdgcn_mfma_f32_32x32x16_bf16(a1, b, acc1, 0, 0, 0);
        }
    }

    const size_t hw = (size_t)HH * WW;
    float* op = out + (size_t)n * C_OUT * hw + (size_t)h * WW + w;
    #pragma unroll
    for (int r = 0; r < 16; ++r) {
        const int o0 = (r & 3) + 8 * (r >> 2) + 4 * hx;
        op[(size_t)o0 * hw]        = acc0[r] + bias[o0];
        op[(size_t)(o0 + 32) * hw] = acc1[r] + bias[o0 + 32];
    }
}

extern "C" void kernel_launch(void* const* d_in, const int* in_sizes, int n_in,
                              void* d_out, int out_size, void* d_ws, size_t ws_size,
                              hipStream_t stream) {
    const float* x     = (const float*)d_in[0];
    const float* theta = (const float*)d_in[1];
    const float* wt    = (const float*)d_in[2];
    const float* bias  = (const float*)d_in[3];
    float* out = (float*)d_out;
    unsigned short* wb = (unsigned short*)d_ws;   // 32 KB bf16 weights

    wt_to_bf16<<<C_OUT * C_IN * 4 / 256, 256, 0, stream>>>(wt, wb);

    dim3 grid(WW / TILE_W, HH / TILE_H, 16);
    steered_conv_mfma<<<grid, 256, 0, stream>>>(x, theta, wb, bias, out);
}

// Round 4
// 45.820 us; speedup vs baseline: 4.6582x; 1.7395x over previous
//
#include <hip/hip_runtime.h>

// Steered 3x3 conv as per-pixel GEMM (K=256 = 64ch x 4 feats) via bf16 MFMA.
// v4: global_load_lds staging + 2-phase async pipeline + TILE_H=8 (shared tap
// rows between vertical pixel pairs) + bijective XCD swizzle.
// B-frag: lane l -> col = l&31 (pixel), k = 16*kc + 8*(l>>5) + r  (verified r2)
// C/D:    col = lane&31, row(o) = (r&3) + 8*(r>>2) + 4*(lane>>5)  (verified r2)

typedef __bf16 bf16x8 __attribute__((ext_vector_type(8)));
typedef float  f32x16 __attribute__((ext_vector_type(16)));
typedef unsigned int u32;
typedef const __attribute__((address_space(1))) u32* gp_t;
typedef __attribute__((address_space(3))) u32* lp_t;

#define HH 128
#define WW 128
#define TILE_H 8
#define TILE_W 32
#define CHCH 16            // channels per chunk
#define NCHUNK 4
#define RROWS 10           // TILE_H + 2
#define RCOLS 40           // staged cols: gw = w0-4 .. w0+35 (16B aligned)
#define CHF (RROWS * RCOLS) // 400 floats per channel
#define CHIMG 65536         // bytes per (n,ch) image plane

__global__ void wt_to_bf16(const float* __restrict__ wt,
                           unsigned short* __restrict__ wb) {
    int i = blockIdx.x * 256 + threadIdx.x;
    union { float f; u32 u; } v; v.f = wt[i];
    wb[i] = (unsigned short)((v.u + 0x7FFF + ((v.u >> 16) & 1)) >> 16);
}

__global__ __launch_bounds__(256, 3) void steered_conv_mfma(
    const float* __restrict__ x, const float* __restrict__ theta,
    const unsigned short* __restrict__ wb, const float* __restrict__ bias,
    float* __restrict__ out)
{
    __shared__ float lds[2][CHCH][CHF];   // 51200 B -> 3 blocks/CU

    const int tid  = threadIdx.x;
    const int wid  = tid >> 6, lane = tid & 63;
    const int pc   = lane & 31, hx = lane >> 5;

    // bijective XCD swizzle: 1024 blocks, 128/XCD = 2 whole images
    const int bb  = blockIdx.x;
    const int swz = (bb & 7) * 128 + (bb >> 3);
    const int n  = swz >> 6;
    const int ty = (swz >> 2) & 15;
    const int tx = swz & 3;
    const int h0 = ty * TILE_H, w0 = tx * TILE_W;
    const int p0 = wid * 2;               // this wave's 2 pixel rows

    // ---- per-lane DMA constants: instr A covers ch bytes [0,1024),
    //      instr B covers [1024,1600) with 36 active lanes ----
    const int oA = lane * 16;
    const int rA = oA / 160;
    const int cA = oA - rA * 160;
    int ghA = h0 - 1 + rA; ghA = ghA < 0 ? 0 : (ghA > 127 ? 127 : ghA);
    int srcA = ghA * 512 + w0 * 4 - 16 + cA;
    srcA = srcA < 0 ? 0 : srcA;
    const bool skA = (w0 == 0 && cA < 16) || (w0 == 96 && cA >= 144);

    const int oB = 1024 + lane * 16;
    const int rB = oB / 160;
    const int cB = oB - rB * 160;
    int ghB = h0 - 1 + rB; ghB = ghB < 0 ? 0 : (ghB > 127 ? 127 : ghB);
    int srcB = ghB * 512 + w0 * 4 - 16 + cB;
    srcB = srcB < 0 ? 0 : (srcB > CHIMG - 16 ? CHIMG - 16 : srcB);
    const bool skB = (lane >= 36) || (w0 == 0 && cB < 16) || (w0 == 96 && cB >= 144);

    const char* xn = (const char*)x + (size_t)n * 64 * CHIMG;
    const bool boundary = (h0 == 0) | (h0 == 120) | (w0 == 0) | (w0 == 96);

    // ---- stage chunk 0 (async DMA; drained by first __syncthreads) ----
    #pragma unroll
    for (int j = 0; j < 4; ++j) {
        const int ch = wid * 4 + j;
        const char* s = xn + ch * CHIMG;
        char* d = (char*)&lds[0][ch][0];
        if (!skA) __builtin_amdgcn_global_load_lds((gp_t)(s + srcA), (lp_t)d, 16, 0, 0);
        if (!skB) __builtin_amdgcn_global_load_lds((gp_t)(s + srcB), (lp_t)(d + 1024), 16, 0, 0);
    }

    // ---- per-pixel harmonics for the wave's two rows ----
    const int wg = w0 + pc;
    const float thA = theta[(n * HH + h0 + p0) * WW + wg];
    const float thB = theta[(n * HH + h0 + p0 + 1) * WW + wg];
    float s1a, c1a, s1b, c1b;
    __sincosf(6.2831853071795864769f * thA, &s1a, &c1a);
    __sincosf(6.2831853071795864769f * thB, &s1b, &c1b);
    const float c2a = 2.f * c1a * c1a - 1.f, s2a = 2.f * s1a * c1a;
    const float c2b = 2.f * c1b * c1b - 1.f, s2b = 2.f * s1b * c1b;

    f32x16 acc00, acc01, acc10, acc11;
    #pragma unroll
    for (int r = 0; r < 16; ++r) { acc00[r]=0.f; acc01[r]=0.f; acc10[r]=0.f; acc11[r]=0.f; }

    const float RS  = 0.35355339059327373f;   // sqrt(2)/4
    const float HMR = 0.14644660940672627f;   // 0.5 - RS

    #pragma unroll 1
    for (int c = 0; c < NCHUNK; ++c) {
        __syncthreads();   // implicit vmcnt(0): chunk c landed; WAR-safe
        if (boundary) {
            float* bz = &lds[c & 1][0][0];
            if (h0 == 0)
                for (int i = tid; i < CHCH * RCOLS; i += 256) bz[(i / RCOLS) * CHF + (i % RCOLS)] = 0.f;
            if (h0 == 120)
                for (int i = tid; i < CHCH * RCOLS; i += 256) bz[(i / RCOLS) * CHF + 9 * RCOLS + (i % RCOLS)] = 0.f;
            if (w0 == 0)
                for (int i = tid; i < CHCH * RROWS; i += 256) bz[(i / RROWS) * CHF + (i % RROWS) * RCOLS + 3] = 0.f;
            if (w0 == 96)
                for (int i = tid; i < CHCH * RROWS; i += 256) bz[(i / RROWS) * CHF + (i % RROWS) * RCOLS + 36] = 0.f;
            __syncthreads();
        }
        if (c < NCHUNK - 1) {   // issue next chunk's DMA; overlaps compute(c)
            const char* xc = xn + (size_t)(c + 1) * CHCH * CHIMG;
            #pragma unroll
            for (int j = 0; j < 4; ++j) {
                const int ch = wid * 4 + j;
                const char* s = xc + ch * CHIMG;
                char* d = (char*)&lds[(c + 1) & 1][ch][0];
                if (!skA) __builtin_amdgcn_global_load_lds((gp_t)(s + srcA), (lp_t)d, 16, 0, 0);
                if (!skB) __builtin_amdgcn_global_load_lds((gp_t)(s + srcB), (lp_t)(d + 1024), 16, 0, 0);
            }
        }
        // ---- compute chunk c: 4 K-steps of 16 (4 channels each) ----
        const float* tb = &lds[c & 1][0][p0 * RCOLS + pc + 3];
        const unsigned short* wk = wb + pc * 256 + c * 64 + hx * 8;
        #pragma unroll
        for (int kc = 0; kc < 4; ++kc) {
            bf16x8 b0, b1;
            #pragma unroll
            for (int cs = 0; cs < 2; ++cs) {
                const float* t = tb + (kc * 4 + hx * 2 + cs) * CHF;
                const float t00=t[0],   t01=t[1],   t02=t[2];
                const float t10=t[40],  t11=t[41],  t12=t[42];
                const float t20=t[80],  t21=t[81],  t22=t[82];
                const float t30=t[120], t31=t[121], t32=t[122];
                const float S0=t00+t01+t02, S1=t10+t11+t12;
                const float S2=t20+t21+t22, S3=t30+t31+t32;
                const float D0=t02-t00, D1=t12-t10, D2=t22-t20, D3=t32-t30;
                {   // pixel row p0 (staged rows 0,1,2)
                    const float F1 = RS * (S0 + S2 + S1 - t11);
                    const float B2 = RS * (D0 + D2) + 0.5f * D1;
                    const float B3 = RS * (S2 - S0) + HMR * (t21 - t01);
                    const float B4 = 0.5f * (S1 - t11 - t01 - t21);
                    const float B5 = 0.5f * (D2 - D0);
                    b0[cs*4+0] = (__bf16)t11;
                    b0[cs*4+1] = (__bf16)F1;
                    b0[cs*4+2] = (__bf16)(c1a * B2 + s1a * B3);
                    b0[cs*4+3] = (__bf16)(c2a * B4 + s2a * B5);
                }
                {   // pixel row p0+1 (staged rows 1,2,3)
                    const float F1 = RS * (S1 + S3 + S2 - t21);
                    const float B2 = RS * (D1 + D3) + 0.5f * D2;
                    const float B3 = RS * (S3 - S1) + HMR * (t31 - t11);
                    const float B4 = 0.5f * (S2 - t21 - t11 - t31);
                    const float B5 = 0.5f * (D3 - D1);
                    b1[cs*4+0] = (__bf16)t21;
                    b1[cs*4+1] = (__bf16)F1;
                    b1[cs*4+2] = (__bf16)(c1b * B2 + s1b * B3);
                    b1[cs*4+3] = (__bf16)(c2b * B4 + s2b * B5);
                }
            }
            const unsigned short* wr = wk + kc * 16;
            const bf16x8 A0 = *(const bf16x8*)wr;
            const bf16x8 A1 = *(const bf16x8*)(wr + 32 * 256);
            acc00 = __builtin_amdgcn_mfma_f32_32x32x16_bf16(A0, b0, acc00, 0, 0, 0);
            acc01 = __builtin_amdgcn_mfma_f32_32x32x16_bf16(A1, b0, acc01, 0, 0, 0);
            acc10 = __builtin_amdgcn_mfma_f32_32x32x16_bf16(A0, b1, acc10, 0, 0, 0);
            acc11 = __builtin_amdgcn_mfma_f32_32x32x16_bf16(A1, b1, acc11, 0, 0, 0);
        }
    }

    const size_t hw = (size_t)HH * WW;
    float* op = out + (size_t)n * 64 * hw + (size_t)(h0 + p0) * WW + w0 + pc;
    #pragma unroll
    for (int r = 0; r < 16; ++r) {
        const int o  = (r & 3) + 8 * (r >> 2) + 4 * hx;
        const float bo = bias[o], bo2 = bias[o + 32];
        op[(size_t)o * hw]             = acc00[r] + bo;
        op[(size_t)(o + 32) * hw]      = acc01[r] + bo2;
        op[(size_t)o * hw + WW]        = acc10[r] + bo;
        op[(size_t)(o + 32) * hw + WW] = acc11[r] + bo2;
    }
}

extern "C" void kernel_launch(void* const* d_in, const int* in_sizes, int n_in,
                              void* d_out, int out_size, void* d_ws, size_t ws_size,
                              hipStream_t stream) {
    const float* x     = (const float*)d_in[0];
    const float* theta = (const float*)d_in[1];
    const float* wt    = (const float*)d_in[2];
    const float* bias  = (const float*)d_in[3];
    float* out = (float*)d_out;
    unsigned short* wb = (unsigned short*)d_ws;   // 32 KB bf16 weights

    wt_to_bf16<<<64, 256, 0, stream>>>(wt, wb);

    steered_conv_mfma<<<1024, 256, 0, stream>>>(x, theta, wb, bias, out);
}